// Round 5
// baseline (319.578 us; speedup 1.0000x reference)
//
#include <hip/hip_runtime.h>

// Sparse 2:4 grouped conv, MI355X.  R7 = R6 with the B-region row-count bug
// fixed (5 -> 6 rows: tiles with l0%56==48 span 4 output rows -> need 6
// padded input rows).  A-operand direct global->VGPR (lane-ordered Wt,
// coalesced), B-only LDS region double-buffered, kc split 4x32, 5 barriers.

#define INF   1152
#define HO    56
#define LOUT  3136      // 56*56
#define XP    58        // padded spatial

typedef __attribute__((ext_vector_type(8))) short bf16x8;
typedef __attribute__((ext_vector_type(4))) float f32x4;

__device__ __forceinline__ unsigned short f2bf(float f) {
  union { float f; unsigned u; } v; v.f = f;
  unsigned r = v.u + 0x7fffu + ((v.u >> 16) & 1u);   // RNE
  return (unsigned short)(r >> 16);
}

__device__ __forceinline__ void async_load16(const void* g, void* l) {
  __builtin_amdgcn_global_load_lds(
      (const __attribute__((address_space(1))) void*)g,
      (__attribute__((address_space(3))) void*)l, 16, 0, 0);
}

// ---------------- fused prep: pad+transpose+cast x  |  gumbel+mask+pack W ------
// blocks [0,3712): xpose (unchanged).  blocks [3712,4864): weight pack into
// LANE-ORDERED layout A2[g*9+tap][kc(4)][ofblk(8)][kq(4)][col(16)][e8(8)]
// so conv's A-fragment load is one coalesced global_load_dwordx4 per (mi).
__global__ __launch_bounds__(256) void prep_kernel(
    const float* __restrict__ x, const float* __restrict__ Ws,
    const float* __restrict__ cw, const float* __restrict__ gb,
    const float* __restrict__ pat,
    unsigned short* __restrict__ Xt, unsigned short* __restrict__ Wt) {
  __shared__ float lds[56 * 129];
  const int t   = threadIdx.x;
  const int bid = blockIdx.x;

  if (bid >= 3712) {                                 // ---- weight pack ----
    int idx = (bid - 3712) * 256 + t;                // 294912 total
    int c   = idx & 127;
    int of  = (idx >> 7) & 127;
    int gt  = idx >> 14;                             // g*9+tap
    int g   = gt / 9;
    int tap = gt - g * 9;
    int e   = ((g << 7) + of) * INF + c * 9 + tap;   // source Ws element
    int q   = e >> 2, pos = e & 3;
    const float* cq = cw + q * 6;
    const float* gq = gb + q * 6;
    float best = cq[0] + gq[0]; int bi = 0;
    #pragma unroll
    for (int j = 1; j < 6; ++j) {
      float v2 = cq[j] + gq[j];
      if (v2 > best) { best = v2; bi = j; }          // strict > = first-max
    }
    // lane-ordered destination
    const int kc = c >> 5, kq = (c >> 3) & 3, e8 = c & 7;
    const int ofb = of >> 4, colA = of & 15;
    const int dst = ((gt * 4 + kc) * 32 + ofb * 4 + kq) * 128 + colA * 8 + e8;
    Wt[dst] = f2bf(Ws[e] * pat[bi * 4 + pos]);
    return;
  }

  // ---- xpose: x (B,256,56,56) f32 -> Xt[bg][58][58][c=128] bf16, zero borders
  const int bg  = bid / 58;
  const int ihp = bid - bg * 58;
  uint4* dst = (uint4*)(Xt + ((bg * XP + ihp) * XP) * 128);
  if (ihp == 0 || ihp == XP - 1) {
    const uint4 z = {0u, 0u, 0u, 0u};
    for (int i = t; i < XP * 16; i += 256) dst[i] = z;
    return;
  }
  const int ih = ihp - 1;
  const float4* src = (const float4*)(x + (bg * 128) * LOUT + ih * HO);
  for (int i = t; i < 128 * 14; i += 256) {
    int c = i / 14, seg = i - c * 14;                // iw = seg*4
    float4 v = src[c * (LOUT / 4) + seg];
    float* row = &lds[(seg * 4) * 129 + c];
    row[0]       = v.x;
    row[129]     = v.y;
    row[2 * 129] = v.z;
    row[3 * 129] = v.w;
  }
  __syncthreads();
  for (int i = t; i < XP * 16; i += 256) {
    int iwp = i >> 4, oct = i & 15;
    uint4 val = {0u, 0u, 0u, 0u};
    if (iwp != 0 && iwp != XP - 1) {
      const float* s = &lds[(iwp - 1) * 129 + (oct << 3)];
      val.x = (unsigned)f2bf(s[0]) | ((unsigned)f2bf(s[1]) << 16);
      val.y = (unsigned)f2bf(s[2]) | ((unsigned)f2bf(s[3]) << 16);
      val.z = (unsigned)f2bf(s[4]) | ((unsigned)f2bf(s[5]) << 16);
      val.w = (unsigned)f2bf(s[6]) | ((unsigned)f2bf(s[7]) << 16);
    }
    dst[i] = val;
  }
}

// ---------------- conv: A in registers, B-region in LDS, 5 barriers ----------
// LDS: sB[2][6 rows][64 pos][32 c] = 2 x 24 KB.  Position swizzle:
// 16B chunk slot = kq ^ ((pos>>1)&3); staged via pre-swizzled global source +
// lane-linear LDS dest; read inverts the same involution -> lane gets chunk kq.
// Loop: kc 0..3 { 9 taps: prefetch next A-frags (coalesced global->reg),
//   tap1: prefetch next kc's B region, 4 ds_read_b128, 16 MFMA }  barrier.
__global__ __launch_bounds__(256, 3) void conv_mfma_kernel(
    const unsigned short* __restrict__ Wt, const unsigned short* __restrict__ Xt,
    float* __restrict__ out) {
  __shared__ __align__(16) unsigned short sB[2][6 * 64 * 32];   // 2 x 24 KB
  const int t  = threadIdx.x;
  const int ln = t & 63, wv = t >> 6;
  const int wm = wv >> 1, wn = wv & 1;
  const int col = ln & 15, kq = ln >> 4;

  // XCD-aware swizzle: contiguous bg range per XCD for L2 locality
  const int lid   = blockIdx.y * 25 + blockIdx.x;
  const int v     = (lid & 7) * 200 + (lid >> 3);
  const int bg    = v / 25;
  const int tileN = v - bg * 25;
  const int g     = bg & 1;
  const int l0    = tileN << 7;
  const int oh0   = l0 / HO;                 // first output row of tile

  // ---- B region staging geometry: 6 loads/thread per kc (one row per round)
  const int iwp0 = t >> 2;                              // 0..63
  const int iwpc = iwp0 > XP - 1 ? XP - 1 : iwp0;       // clamp
  const int csrc = (t & 3) ^ ((iwp0 >> 1) & 3);         // pre-swizzled chunk
  const int xbase = bg * (XP * XP * 128);

  // ---- B read geometry: per-lane position base per ni (tap 0,0)
  int pb[4];
  #pragma unroll
  for (int ni = 0; ni < 4; ++ni) {
    int l = l0 + (wn << 6) + (ni << 4) + col;
    if (l > LOUT - 1) l = LOUT - 1;
    int oh = l / HO, ow = l - oh * HO;
    pb[ni] = ((oh - oh0) << 6) + ow;
  }

  // ---- A: coalesced fragment base (shorts); per (kc,tap) add (tap*4+kc)*4096
  const unsigned short* aptr = Wt + (g * 9 * 4) * 4096 + wm * 2048 + ln * 8;

  f32x4 acc[4][4];
  #pragma unroll
  for (int i = 0; i < 4; ++i)
    #pragma unroll
    for (int j = 0; j < 4; ++j) acc[i][j] = (f32x4){0.f, 0.f, 0.f, 0.f};

  auto stageRegion = [&](int kcR, int buf) {
    const int c0 = kcR << 5;
    #pragma unroll
    for (int it = 0; it < 6; ++it) {
      int ihp = oh0 + it; if (ihp > XP - 1) ihp = XP - 1;
      async_load16(Xt + xbase + (ihp * XP + iwpc) * 128 + c0 + (csrc << 3),
                   &sB[buf][it * 2048 + t * 8]);
    }
  };

  auto loadA = [&](int kcL, int tapL, bf16x8* dst) {
    const unsigned short* p = aptr + (tapL * 4 + kcL) * 4096;
    #pragma unroll
    for (int mi = 0; mi < 4; ++mi) dst[mi] = *(const bf16x8*)(p + mi * 512);
  };

  bf16x8 afA[4], afB[4];
  stageRegion(0, 0);
  loadA(0, 0, afA);
  __syncthreads();                                   // region0 + af0 landed

  #pragma unroll 1
  for (int kc = 0; kc < 4; ++kc) {
    const int cur = kc & 1;
    #pragma unroll
    for (int tap = 0; tap < 9; ++tap) {
      const bool last = (kc == 3 && tap == 8);
      if (!last)                                     // prefetch next A-frags
        loadA(tap == 8 ? kc + 1 : kc, tap == 8 ? 0 : tap + 1, afB);
      if (tap == 1 && kc < 3) stageRegion(kc + 1, cur ^ 1);  // prefetch region
      const int th = tap / 3, tw = tap - th * 3;     // compile-time (unrolled)
      bf16x8 bfr[4];
      #pragma unroll
      for (int ni = 0; ni < 4; ++ni) {
        const int pos = pb[ni] + (th << 6) + tw;
        bfr[ni] = *(const bf16x8*)
            &sB[cur][pos * 32 + ((kq ^ ((pos >> 1) & 3)) << 3)];
      }
      #pragma unroll
      for (int mi = 0; mi < 4; ++mi)
        #pragma unroll
        for (int ni = 0; ni < 4; ++ni)
          acc[mi][ni] = __builtin_amdgcn_mfma_f32_16x16x32_bf16(
              afA[mi], bfr[ni], acc[mi][ni], 0, 0, 0);
      if (!last) {
        #pragma unroll
        for (int mi = 0; mi < 4; ++mi) afA[mi] = afB[mi];
      }
    }
    __syncthreads();   // drains vmcnt(0): next region + next af landed;
  }                    // also WAR-guards buf[cur] before kc+1's stage

  // epilogue: C/D layout col=lane&15, row=(lane>>4)*4+reg
  const int rowq = kq << 2;
  #pragma unroll
  for (int mi = 0; mi < 4; ++mi) {
    #pragma unroll
    for (int ni = 0; ni < 4; ++ni) {
      const int l = l0 + (wn << 6) + (ni << 4) + col;
      if (l < LOUT) {
        #pragma unroll
        for (int r = 0; r < 4; ++r) {
          const int of = (wm << 6) + (mi << 4) + rowq + r;
          out[(bg * 128 + of) * LOUT + l] = acc[mi][ni][r];
        }
      }
    }
  }
}

extern "C" void kernel_launch(void* const* d_in, const int* in_sizes, int n_in,
                              void* d_out, int out_size, void* d_ws, size_t ws_size,
                              hipStream_t stream) {
  const float* x   = (const float*)d_in[0];
  const float* Ws  = (const float*)d_in[1];
  const float* cw  = (const float*)d_in[2];
  const float* gb  = (const float*)d_in[3];
  const float* pat = (const float*)d_in[4];
  float* out = (float*)d_out;

  unsigned short* Wt = (unsigned short*)d_ws;                       // 576 KB
  unsigned short* Xt = (unsigned short*)((char*)d_ws + (1 << 20));  // 55 MB

  prep_kernel<<<4864, 256, 0, stream>>>(x, Ws, cw, gb, pat, Xt, Wt);
  conv_mfma_kernel<<<dim3(25, 64), 256, 0, stream>>>(Wt, Xt, out);
}

// Round 11
// 272.931 us; speedup vs baseline: 1.1709x; 1.1709x over previous
//
#include <hip/hip_runtime.h>

// Sparse 2:4 grouped conv, MI355X.  R8 (5th resubmit — five consecutive GPU
// acquisition timeouts, never measured): R3 structure (32 KB LDS, 4 blocks/CU)
// + counted-vmcnt pipeline: BK=32 double-buffered, per stage
//   bar1 / issue(s+1) / s_waitcnt vmcnt(4) / bar2 / 16 MFMA
// so the next stage's 4 loads/thread stay in flight across both barriers
// (T3+T4; R4 proved drain-0 dbuf is null, catalog says the gain IS the count).
// Prep is the R3 version (linear Wt).  Post-mortem R7: A-from-global thrashed
// L2 (FETCH 197 MB, WRITE 190 MB) -> keep both operands LDS-staged.

#define INF   1152
#define HO    56
#define LOUT  3136      // 56*56
#define XP    58        // padded spatial

typedef __attribute__((ext_vector_type(8))) short bf16x8;
typedef __attribute__((ext_vector_type(4))) float f32x4;

__device__ __forceinline__ unsigned short f2bf(float f) {
  union { float f; unsigned u; } v; v.f = f;
  unsigned r = v.u + 0x7fffu + ((v.u >> 16) & 1u);   // RNE
  return (unsigned short)(r >> 16);
}

__device__ __forceinline__ void async_load16(const void* g, void* l) {
  __builtin_amdgcn_global_load_lds(
      (const __attribute__((address_space(1))) void*)g,
      (__attribute__((address_space(3))) void*)l, 16, 0, 0);
}

// ---------------- fused prep: pad+transpose+cast x  |  gumbel+mask+pack W ------
// blocks [0,3712): xpose (bg=bid/58, ihp=bid%58)
// blocks [3712,4864): Wt[g][tap][of][c] pack with inline gumbel argmax (R3)
__global__ __launch_bounds__(256) void prep_kernel(
    const float* __restrict__ x, const float* __restrict__ Ws,
    const float* __restrict__ cw, const float* __restrict__ gb,
    const float* __restrict__ pat,
    unsigned short* __restrict__ Xt, unsigned short* __restrict__ Wt) {
  __shared__ float lds[56 * 129];
  const int t   = threadIdx.x;
  const int bid = blockIdx.x;

  if (bid >= 3712) {                                 // ---- weight pack ----
    int idx = (bid - 3712) * 256 + t;                // 294912 total
    int c   = idx & 127;
    int of  = (idx >> 7) & 127;
    int gt  = idx >> 14;                             // g*9+tap
    int g   = gt / 9;
    int tap = gt - g * 9;
    int e   = ((g << 7) + of) * INF + c * 9 + tap;
    int q   = e >> 2, pos = e & 3;
    const float* cq = cw + q * 6;
    const float* gq = gb + q * 6;
    float best = cq[0] + gq[0]; int bi = 0;
    #pragma unroll
    for (int j = 1; j < 6; ++j) {
      float v2 = cq[j] + gq[j];
      if (v2 > best) { best = v2; bi = j; }          // strict > = first-max
    }
    Wt[idx] = f2bf(Ws[e] * pat[bi * 4 + pos]);
    return;
  }

  // ---- xpose: x (B,256,56,56) f32 -> Xt[bg][58][58][c=128] bf16, zero borders
  const int bg  = bid / 58;
  const int ihp = bid - bg * 58;
  uint4* dst = (uint4*)(Xt + ((bg * XP + ihp) * XP) * 128);
  if (ihp == 0 || ihp == XP - 1) {
    const uint4 z = {0u, 0u, 0u, 0u};
    for (int i = t; i < XP * 16; i += 256) dst[i] = z;
    return;
  }
  const int ih = ihp - 1;
  const float4* src = (const float4*)(x + (bg * 128) * LOUT + ih * HO);
  for (int i = t; i < 128 * 14; i += 256) {
    int c = i / 14, seg = i - c * 14;                // iw = seg*4
    float4 v = src[c * (LOUT / 4) + seg];
    float* row = &lds[(seg * 4) * 129 + c];
    row[0]       = v.x;
    row[129]     = v.y;
    row[2 * 129] = v.z;
    row[3 * 129] = v.w;
  }
  __syncthreads();
  for (int i = t; i < XP * 16; i += 256) {
    int iwp = i >> 4, oct = i & 15;
    uint4 val = {0u, 0u, 0u, 0u};
    if (iwp != 0 && iwp != XP - 1) {
      const float* s = &lds[(iwp - 1) * 129 + (oct << 3)];
      val.x = (unsigned)f2bf(s[0]) | ((unsigned)f2bf(s[1]) << 16);
      val.y = (unsigned)f2bf(s[2]) | ((unsigned)f2bf(s[3]) << 16);
      val.z = (unsigned)f2bf(s[4]) | ((unsigned)f2bf(s[5]) << 16);
      val.w = (unsigned)f2bf(s[6]) | ((unsigned)f2bf(s[7]) << 16);
    }
    dst[i] = val;
  }
}

// ---------------- conv: BK=32 dbuf, counted vmcnt pipeline, 32 KB LDS --------
// LDS row = 32 c = 4 chunks of 16B (64 B rows).  chunk (row,slot) holds
// logical chunk slot^((row>>1)&3); read slot = kq^((col>>1)&3) -> chunk kq.
// Bank check: granule (row*4+slot)&7 is uniform 8 lanes/granule over the
// wave's 64-lane ds_read_b128 -> conflict-free.
// Stage s: tap = s>>2, kc = s&3 (tap-major preserves B L2 locality).
// Per stage: bar1 (WAR: reads of s-1 done) / issue s+1 (4 loads/thread) /
// s_waitcnt vmcnt(4) (stage-s loads done, s+1's stay in flight) / bar2 /
// setprio(1) 16 MFMA setprio(0).
__global__ __launch_bounds__(256, 4) void conv_mfma_kernel(
    const unsigned short* __restrict__ Wt, const unsigned short* __restrict__ Xt,
    float* __restrict__ out) {
  __shared__ __align__(16) unsigned short sA[2][128 * 32];   // 2 x 8 KB
  __shared__ __align__(16) unsigned short sB[2][128 * 32];   // 2 x 8 KB
  const int t  = threadIdx.x;
  const int ln = t & 63, wv = t >> 6;
  const int wm = wv >> 1, wn = wv & 1;
  const int col = ln & 15, kq = ln >> 4;

  // XCD-aware swizzle: contiguous bg range per XCD for L2 locality
  const int lid   = blockIdx.y * 25 + blockIdx.x;
  const int v     = (lid & 7) * 200 + (lid >> 3);
  const int bg    = v / 25;
  const int tileN = v - bg * 25;
  const int g     = bg & 1;
  const int l0    = tileN << 7;

  // ---- staging geometry: 2 loads per operand per thread per stage
  const int rl = ln >> 2;                        // row within 16-row group
  const int ch = (ln & 3) ^ ((ln >> 3) & 3);     // pre-swizzled source chunk
  int arow[2], brow[2];
  #pragma unroll
  for (int i = 0; i < 2; ++i) {
    const int row = (wv << 5) + (i << 4) + rl;   // 0..127
    arow[i] = (row << 7) + (ch << 3);            // of*128 + chunk*8
    int ll = l0 + row;
    if (ll > LOUT - 1) ll = LOUT - 1;            // tail tile: clamp
    int oh = ll / HO, ow = ll - oh * HO;
    brow[i] = ((bg * XP + oh) * XP + ow) * 128 + (ch << 3);
  }

  // ---- read offsets (shorts): row*32 + slot*8, slot = kq^((col>>1)&3)
  const int slot8 = (kq ^ ((col >> 1) & 3)) << 3;
  int aoff[4], boff[4];
  #pragma unroll
  for (int i = 0; i < 4; ++i) {
    aoff[i] = (((wm << 6) + (i << 4) + col) << 5) + slot8;
    boff[i] = (((wn << 6) + (i << 4) + col) << 5) + slot8;
  }

  f32x4 acc[4][4];
  #pragma unroll
  for (int i = 0; i < 4; ++i)
    #pragma unroll
    for (int j = 0; j < 4; ++j) acc[i][j] = (f32x4){0.f, 0.f, 0.f, 0.f};

  auto issue = [&](int s, int b) {
    const int tap = s >> 2, kc = s & 3;
    const int c0  = kc << 5;
    const int th  = (tap * 11) >> 5;             // tap/3 for tap in [0,9)
    const int tw  = tap - th * 3;
    const int aT  = ((g * 9 + tap) << 14) + c0;
    const int bT  = ((th * XP + tw) << 7) + c0;
    #pragma unroll
    for (int i = 0; i < 2; ++i) {
      const int lb = (wv << 10) + (i << 9);      // wave-uniform LDS base
      async_load16(Wt + aT + arow[i], &sA[b][lb]);
      async_load16(Xt + bT + brow[i], &sB[b][lb]);
    }
  };

  issue(0, 0);

  #pragma unroll 1
  for (int s = 0; s < 36; ++s) {
    const int cur = s & 1;
    __builtin_amdgcn_s_barrier();                // WAR: reads of s-1 complete
    if (s < 35) {
      issue(s + 1, cur ^ 1);
      asm volatile("s_waitcnt vmcnt(4)" ::: "memory");   // stage-s landed,
    } else {                                             // s+1 in flight
      asm volatile("s_waitcnt vmcnt(0)" ::: "memory");
    }
    __builtin_amdgcn_sched_barrier(0);
    __builtin_amdgcn_s_barrier();                // all waves' stage-s visible

    __builtin_amdgcn_s_setprio(1);
    bf16x8 af[4], bfr[4];
    #pragma unroll
    for (int mi = 0; mi < 4; ++mi)
      af[mi] = *(const bf16x8*)&sA[cur][aoff[mi]];
    #pragma unroll
    for (int ni = 0; ni < 4; ++ni)
      bfr[ni] = *(const bf16x8*)&sB[cur][boff[ni]];
    #pragma unroll
    for (int mi = 0; mi < 4; ++mi)
      #pragma unroll
      for (int ni = 0; ni < 4; ++ni)
        acc[mi][ni] = __builtin_amdgcn_mfma_f32_16x16x32_bf16(
            af[mi], bfr[ni], acc[mi][ni], 0, 0, 0);
    __builtin_amdgcn_s_setprio(0);
  }

  // epilogue: C/D layout col=lane&15, row=(lane>>4)*4+reg
  const int rowq = kq << 2;
  #pragma unroll
  for (int mi = 0; mi < 4; ++mi) {
    #pragma unroll
    for (int ni = 0; ni < 4; ++ni) {
      const int l = l0 + (wn << 6) + (ni << 4) + col;
      if (l < LOUT) {
        #pragma unroll
        for (int r = 0; r < 4; ++r) {
          const int of = (wm << 6) + (mi << 4) + rowq + r;
          out[(bg * 128 + of) * LOUT + l] = acc[mi][ni][r];
        }
      }
    }
  }
}

extern "C" void kernel_launch(void* const* d_in, const int* in_sizes, int n_in,
                              void* d_out, int out_size, void* d_ws, size_t ws_size,
                              hipStream_t stream) {
  const float* x   = (const float*)d_in[0];
  const float* Ws  = (const float*)d_in[1];
  const float* cw  = (const float*)d_in[2];
  const float* gb  = (const float*)d_in[3];
  const float* pat = (const float*)d_in[4];
  float* out = (float*)d_out;

  unsigned short* Wt = (unsigned short*)d_ws;                       // 576 KB
  unsigned short* Xt = (unsigned short*)((char*)d_ws + (1 << 20));  // 55 MB

  prep_kernel<<<4864, 256, 0, stream>>>(x, Ws, cw, gb, pat, Xt, Wt);
  conv_mfma_kernel<<<dim3(25, 64), 256, 0, stream>>>(Wt, Xt, out);
}